// Round 1
// baseline (753.299 us; speedup 1.0000x reference)
//
#include <hip/hip_runtime.h>
#include <math.h>

#define BSZ 8
#define NSQ 1024
#define DM  512
#define HH  8
#define HDIM 64
#define MROWS 8192
#define TOPK 32

// ---------------------------------------------------------------------------
// GEMM: C[M=8192, N=512] = act(A[8192,512] @ W[512,512] + bias) * scale + R
// 128x128 tile, 8x8 per thread, BK=32, 256 threads.
// ---------------------------------------------------------------------------
__global__ __launch_bounds__(256) void gemm_kernel(
    const float* __restrict__ A, const float* __restrict__ W,
    const float* __restrict__ bias, const float* __restrict__ R,
    float* __restrict__ C, int relu, float scale)
{
    __shared__ float As[32][132];
    __shared__ float Bs[32][132];
    const int tid  = threadIdx.x;
    const int row0 = blockIdx.x * 128;
    const int col0 = blockIdx.y * 128;
    const int ty = tid >> 4, tx = tid & 15;

    float acc[8][8];
#pragma unroll
    for (int i = 0; i < 8; ++i)
#pragma unroll
        for (int j = 0; j < 8; ++j) acc[i][j] = 0.f;

    const int ak4 = tid & 7,  arr = tid >> 3;   // A staging: 8 k-groups x 32 rows
    const int bc4 = tid & 31, bkr = tid >> 5;   // B staging: 32 col-groups x 8 k-rows

    for (int k0 = 0; k0 < DM; k0 += 32) {
#pragma unroll
        for (int p = 0; p < 4; ++p) {
            int row = arr + p * 32;
            float4 av = *(const float4*)(A + (size_t)(row0 + row) * DM + k0 + ak4 * 4);
            As[ak4*4+0][row] = av.x; As[ak4*4+1][row] = av.y;
            As[ak4*4+2][row] = av.z; As[ak4*4+3][row] = av.w;
            int kk = bkr + p * 8;
            float4 wv = *(const float4*)(W + (size_t)(k0 + kk) * DM + col0 + bc4 * 4);
            *(float4*)&Bs[kk][bc4*4] = wv;
        }
        __syncthreads();
#pragma unroll 8
        for (int kk = 0; kk < 32; ++kk) {
            float a[8], bf[8];
            *(float4*)&a[0]  = *(const float4*)&As[kk][ty*8];
            *(float4*)&a[4]  = *(const float4*)&As[kk][ty*8+4];
            *(float4*)&bf[0] = *(const float4*)&Bs[kk][tx*8];
            *(float4*)&bf[4] = *(const float4*)&Bs[kk][tx*8+4];
#pragma unroll
            for (int i = 0; i < 8; ++i)
#pragma unroll
                for (int j = 0; j < 8; ++j)
                    acc[i][j] = fmaf(a[i], bf[j], acc[i][j]);
        }
        __syncthreads();
    }

    float bcol[8];
    *(float4*)&bcol[0] = *(const float4*)(bias + col0 + tx*8);
    *(float4*)&bcol[4] = *(const float4*)(bias + col0 + tx*8 + 4);
#pragma unroll
    for (int i = 0; i < 8; ++i) {
        size_t off = (size_t)(row0 + ty*8 + i) * DM + col0 + tx*8;
        float o[8];
#pragma unroll
        for (int j = 0; j < 8; ++j) {
            float t = acc[i][j] + bcol[j];
            if (relu) t = fmaxf(t, 0.f);
            o[j] = t * scale;
        }
        if (R) {
            float4 r0v = *(const float4*)(R + off);
            float4 r1v = *(const float4*)(R + off + 4);
            o[0]+=r0v.x; o[1]+=r0v.y; o[2]+=r0v.z; o[3]+=r0v.w;
            o[4]+=r1v.x; o[5]+=r1v.y; o[6]+=r1v.z; o[7]+=r1v.w;
        }
        *(float4*)(C + off)     = make_float4(o[0],o[1],o[2],o[3]);
        *(float4*)(C + off + 4) = make_float4(o[4],o[5],o[6],o[7]);
    }
}

// ---------------------------------------------------------------------------
// Scores: per head-batch hb: S[1024,1024] = q_hb[1024,64] @ k_hb[1024,64]^T
// hb = h*B + b; row n of q_hb lives at q[(b*N+n)*D + h*64 .. +63]
// 128x128 tile, 8x8 per thread, K=64 in two BK=32 chunks.
// ---------------------------------------------------------------------------
__global__ __launch_bounds__(256) void score_gemm(
    const float* __restrict__ q, const float* __restrict__ kb,
    float* __restrict__ scores, int hb0)
{
    __shared__ float As[32][132];
    __shared__ float Bs[32][132];
    const int tid = threadIdx.x;
    const int hb = hb0 + blockIdx.z;
    const int h = hb >> 3, b = hb & 7;
    const int r0 = blockIdx.x * 128;
    const int c0 = blockIdx.y * 128;
    const int ty = tid >> 4, tx = tid & 15;

    float acc[8][8];
#pragma unroll
    for (int i = 0; i < 8; ++i)
#pragma unroll
        for (int j = 0; j < 8; ++j) acc[i][j] = 0.f;

    const int k4 = tid & 7, rr = tid >> 3;
    const size_t base = (size_t)b * NSQ * DM + (size_t)h * HDIM;

    for (int kc = 0; kc < 64; kc += 32) {
#pragma unroll
        for (int p = 0; p < 4; ++p) {
            int row = rr + p * 32;
            float4 qv = *(const float4*)(q  + base + (size_t)(r0 + row) * DM + kc + k4*4);
            As[k4*4+0][row]=qv.x; As[k4*4+1][row]=qv.y; As[k4*4+2][row]=qv.z; As[k4*4+3][row]=qv.w;
            float4 kv = *(const float4*)(kb + base + (size_t)(c0 + row) * DM + kc + k4*4);
            Bs[k4*4+0][row]=kv.x; Bs[k4*4+1][row]=kv.y; Bs[k4*4+2][row]=kv.z; Bs[k4*4+3][row]=kv.w;
        }
        __syncthreads();
#pragma unroll 8
        for (int kk = 0; kk < 32; ++kk) {
            float a[8], bf[8];
            *(float4*)&a[0]  = *(const float4*)&As[kk][ty*8];
            *(float4*)&a[4]  = *(const float4*)&As[kk][ty*8+4];
            *(float4*)&bf[0] = *(const float4*)&Bs[kk][tx*8];
            *(float4*)&bf[4] = *(const float4*)&Bs[kk][tx*8+4];
#pragma unroll
            for (int i = 0; i < 8; ++i)
#pragma unroll
                for (int j = 0; j < 8; ++j)
                    acc[i][j] = fmaf(a[i], bf[j], acc[i][j]);
        }
        __syncthreads();
    }

    float* srow = scores + ((size_t)blockIdx.z * NSQ + r0) * NSQ + c0;
#pragma unroll
    for (int i = 0; i < 8; ++i) {
        size_t off = (size_t)(ty*8 + i) * NSQ + tx*8;
        *(float4*)(srow + off)     = make_float4(acc[i][0],acc[i][1],acc[i][2],acc[i][3]);
        *(float4*)(srow + off + 4) = make_float4(acc[i][4],acc[i][5],acc[i][6],acc[i][7]);
    }
}

// ---------------------------------------------------------------------------
// Top-32 selection (exact, fp32) + softmax + PV.
// One wave per query row; 16 scores/lane in registers; bisection on
// ordered-uint bits using ballot+popcount (no DS shuffles in hot loop).
// ---------------------------------------------------------------------------
__global__ __launch_bounds__(256) void select_pv(
    const float* __restrict__ scores, const float* __restrict__ v,
    float* __restrict__ attn_out, int hb0)
{
    __shared__ float pvals[4][TOPK];
    __shared__ int   pidx[4][TOPK];
    __shared__ int   cnt[4];

    const int tid = threadIdx.x;
    const int w = tid >> 6, lane = tid & 63;
    const int hbz = blockIdx.y;
    const int hb = hb0 + hbz;
    const int h = hb >> 3, b = hb & 7;
    const int row = blockIdx.x * 4 + w;

    const float* srow = scores + ((size_t)hbz * NSQ + row) * NSQ;

    float f[16]; unsigned u[16];
#pragma unroll
    for (int i = 0; i < 16; ++i) f[i] = srow[i * 64 + lane];
#pragma unroll
    for (int i = 0; i < 16; ++i) {
        unsigned bits = __float_as_uint(f[i]);
        u[i] = bits ^ (0x80000000u | (unsigned)((int)bits >> 31));
    }

    // bisection: c(t) = #{u > t}; invariant c(lo) >= 32 > c(hi)
    unsigned lo = 0u, hi = 0xFFFFFFFFu;
    int clo = 1024;
    while (hi - lo > 1u) {
        unsigned mid = lo + ((hi - lo) >> 1);
        int c = 0;
#pragma unroll
        for (int i = 0; i < 16; ++i) c += (int)(u[i] > mid);
        int tot = 0;
        tot += __popcll(__ballot(c & 1));
        tot += __popcll(__ballot(c & 2)) << 1;
        tot += __popcll(__ballot(c & 4)) << 2;
        tot += __popcll(__ballot(c & 8)) << 3;
        tot += __popcll(__ballot(c & 16)) << 4;
        if (tot >= TOPK) { lo = mid; clo = tot; if (tot == TOPK) break; }
        else hi = mid;
    }

    unsigned selm = 0;
#pragma unroll
    for (int i = 0; i < 16; ++i) if (u[i] > lo) selm |= (1u << i);

    // tie-prune (rare: exact duplicate at the boundary value hi = lo+1):
    int nsel = clo;
    unsigned bhi = lo + 1u;
    while (nsel > TOPK) {
        int myidx = -1, myslot = 0;
#pragma unroll
        for (int i = 0; i < 16; ++i)
            if (((selm >> i) & 1u) && u[i] == bhi) { myidx = i * 64 + lane; myslot = i; }
        int mx = myidx;
#pragma unroll
        for (int o = 32; o; o >>= 1) mx = max(mx, __shfl_xor(mx, o));
        if (myidx == mx && myidx >= 0) selm &= ~(1u << myslot);
        nsel--;
    }

    // softmax over the selected 32
    float lm = -INFINITY;
#pragma unroll
    for (int i = 0; i < 16; ++i) if ((selm >> i) & 1u) lm = fmaxf(lm, f[i]);
#pragma unroll
    for (int o = 32; o; o >>= 1) lm = fmaxf(lm, __shfl_xor(lm, o));

    float e[16]; float lsum = 0.f;
#pragma unroll
    for (int i = 0; i < 16; ++i) {
        e[i] = ((selm >> i) & 1u) ? __expf(f[i] - lm) : 0.f;
        lsum += e[i];
    }
#pragma unroll
    for (int o = 32; o; o >>= 1) lsum += __shfl_xor(lsum, o);
    float inv = 1.f / lsum;

    if (lane == 0) cnt[w] = 0;
    __syncthreads();
#pragma unroll
    for (int i = 0; i < 16; ++i) {
        if ((selm >> i) & 1u) {
            int s = atomicAdd(&cnt[w], 1);
            pvals[w][s] = e[i] * inv;
            pidx[w][s]  = i * 64 + lane;
        }
    }
    __syncthreads();

    float acc = 0.f;
    const float* vbase = v + (size_t)b * NSQ * DM + (size_t)h * HDIM + lane;
#pragma unroll 4
    for (int t = 0; t < TOPK; ++t) {
        float p = pvals[w][t];
        int j   = pidx[w][t];
        acc = fmaf(p, vbase[(size_t)j * DM], acc);
    }
    attn_out[((size_t)b * NSQ + row) * DM + (size_t)h * HDIM + lane] = acc;
}

// ---------------------------------------------------------------------------
// LayerNorm over last dim (512): out = LN(a [+ b2]) * g + beta
// one row per block, 256 threads x float2
// ---------------------------------------------------------------------------
__global__ __launch_bounds__(256) void ln_kernel(
    const float* __restrict__ a, const float* __restrict__ b2,
    const float* __restrict__ g, const float* __restrict__ beta,
    float* __restrict__ out)
{
    __shared__ float red[4][2];
    const int row = blockIdx.x, tid = threadIdx.x;
    const int w = tid >> 6;

    float2 v0 = ((const float2*)(a + (size_t)row * DM))[tid];
    if (b2) {
        float2 bv = ((const float2*)(b2 + (size_t)row * DM))[tid];
        v0.x += bv.x; v0.y += bv.y;
    }
    float s  = v0.x + v0.y;
    float sq = v0.x * v0.x + v0.y * v0.y;
#pragma unroll
    for (int o = 32; o; o >>= 1) { s += __shfl_xor(s, o); sq += __shfl_xor(sq, o); }
    if ((tid & 63) == 0) { red[w][0] = s; red[w][1] = sq; }
    __syncthreads();
    float S = 0.f, Q = 0.f;
#pragma unroll
    for (int i = 0; i < 4; ++i) { S += red[i][0]; Q += red[i][1]; }
    float mu  = S * (1.f / DM);
    float var = Q * (1.f / DM) - mu * mu;
    float rs  = rsqrtf(var + 1e-5f);
    float2 gv = ((const float2*)g)[tid];
    float2 bv = ((const float2*)beta)[tid];
    float2 o;
    o.x = (v0.x - mu) * rs * gv.x + bv.x;
    o.y = (v0.y - mu) * rs * gv.y + bv.y;
    ((float2*)(out + (size_t)row * DM))[tid] = o;
}

// ---------------------------------------------------------------------------
extern "C" void kernel_launch(void* const* d_in, const int* in_sizes, int n_in,
                              void* d_out, int out_size, void* d_ws, size_t ws_size,
                              hipStream_t stream) {
    const float* src = (const float*)d_in[0];
    const float* tgt = (const float*)d_in[1];
    const float* Wq  = (const float*)d_in[2];
    const float* bq  = (const float*)d_in[3];
    const float* Wk  = (const float*)d_in[4];
    const float* bk  = (const float*)d_in[5];
    const float* Wv  = (const float*)d_in[6];
    const float* bv  = (const float*)d_in[7];
    const float* W1  = (const float*)d_in[8];
    const float* b1  = (const float*)d_in[9];
    const float* W2  = (const float*)d_in[10];
    const float* b2  = (const float*)d_in[11];
    const float* g1  = (const float*)d_in[12];
    const float* be1 = (const float*)d_in[13];
    const float* g2  = (const float*)d_in[14];
    const float* be2 = (const float*)d_in[15];

    float* ws = (float*)d_ws;
    const size_t BUF = (size_t)MROWS * DM;   // 4,194,304 floats = 16 MB
    float* qb   = ws;
    float* kbuf = ws + BUF;
    float* vbuf = ws + 2*BUF;
    float* ao   = ws + 3*BUF;   // attn out, later x+ff
    float* xb   = ws + 4*BUF;
    float* hbuf = ws + 5*BUF;
    float* sc   = ws + 6*BUF;   // scores slab region

    const size_t fixed_bytes = 6 * BUF * sizeof(float);          // 96 MB
    const size_t per_hb      = (size_t)NSQ * NSQ * sizeof(float); // 4 MB
    size_t avail = ws_size > fixed_bytes ? ws_size - fixed_bytes : 0;
    int slab = (int)(avail / per_hb);
    if (slab < 1)  slab = 1;
    if (slab > 64) slab = 64;

    dim3 blk(256);
    const float qscale = 0.04419417382415922f;  // 1/sqrt(512)

    gemm_kernel<<<dim3(64, 4), blk, 0, stream>>>(tgt, Wq, bq, nullptr, qb,   0, qscale);
    gemm_kernel<<<dim3(64, 4), blk, 0, stream>>>(src, Wk, bk, nullptr, kbuf, 0, 1.f);
    gemm_kernel<<<dim3(64, 4), blk, 0, stream>>>(src, Wv, bv, nullptr, vbuf, 0, 1.f);

    for (int hb0 = 0; hb0 < 64; hb0 += slab) {
        int c = 64 - hb0; if (c > slab) c = slab;
        score_gemm<<<dim3(8, 8, c), blk, 0, stream>>>(qb, kbuf, sc, hb0);
        select_pv<<<dim3(256, c), blk, 0, stream>>>(sc, vbuf, ao, hb0);
    }

    ln_kernel<<<dim3(MROWS), blk, 0, stream>>>(tgt, ao, g1, be1, xb);
    gemm_kernel<<<dim3(64, 4), blk, 0, stream>>>(xb,   W1, b1, nullptr, hbuf, 1, 1.f);
    gemm_kernel<<<dim3(64, 4), blk, 0, stream>>>(hbuf, W2, b2, xb,      ao,   0, 1.f);
    ln_kernel<<<dim3(MROWS), blk, 0, stream>>>(ao, nullptr, g2, be2, (float*)d_out);
}

// Round 2
// 456.284 us; speedup vs baseline: 1.6509x; 1.6509x over previous
//
#include <hip/hip_runtime.h>
#include <math.h>

#define NSQ 1024
#define DM  512
#define HDIM 64
#define MROWS 8192
#define TOPK 32

typedef unsigned short u16;
typedef __attribute__((ext_vector_type(8))) short bf16x8;
typedef __attribute__((ext_vector_type(4))) float f32x4;

#define MFMA_B16(A,B,C) __builtin_amdgcn_mfma_f32_16x16x32_bf16(A,B,C,0,0,0)

__device__ __forceinline__ unsigned f2b(float x) {
    unsigned u = __float_as_uint(x);
    return (u + 0x7FFFu + ((u >> 16) & 1u)) >> 16;   // RN-even to bf16 bits
}
__device__ __forceinline__ float b2f(unsigned h) { return __uint_as_float(h << 16); }
__device__ __forceinline__ unsigned ordu(float f) {
    unsigned b = __float_as_uint(f);
    return b ^ (0x80000000u | (unsigned)((int)b >> 31));  // order-preserving uint
}

// ---------------------------------------------------------------------------
// fp32 [8192x512] -> bf16 hi/lo planes
// ---------------------------------------------------------------------------
__global__ __launch_bounds__(256) void conv_split(
    const float* __restrict__ x, u16* __restrict__ hi, u16* __restrict__ lo)
{
    int idx = blockIdx.x * 256 + threadIdx.x;
    float4 v = ((const float4*)x)[idx];
    float f[4] = {v.x, v.y, v.z, v.w};
    ushort4 hv, lv;
    unsigned h;
    h = f2b(f[0]); hv.x = (u16)h; lv.x = (u16)f2b(f[0] - b2f(h));
    h = f2b(f[1]); hv.y = (u16)h; lv.y = (u16)f2b(f[1] - b2f(h));
    h = f2b(f[2]); hv.z = (u16)h; lv.z = (u16)f2b(f[2] - b2f(h));
    h = f2b(f[3]); hv.w = (u16)h; lv.w = (u16)f2b(f[3] - b2f(h));
    ((ushort4*)hi)[idx] = hv;
    ((ushort4*)lo)[idx] = lv;
}

// ---------------------------------------------------------------------------
// W[512,512] (row-major, k-major) -> transposed bf16 hi/lo planes Wt[n][k]
// ---------------------------------------------------------------------------
__global__ __launch_bounds__(256) void wconv(
    const float* __restrict__ W, u16* __restrict__ thi, u16* __restrict__ tlo)
{
    __shared__ float T[32][33];
    const int tx = threadIdx.x & 31, ty = threadIdx.x >> 5;
    const int n0 = blockIdx.x * 32, k0 = blockIdx.y * 32;
#pragma unroll
    for (int p = 0; p < 4; ++p) {
        int r = ty + p * 8;
        T[r][tx] = W[(size_t)(k0 + r) * DM + n0 + tx];
    }
    __syncthreads();
#pragma unroll
    for (int p = 0; p < 4; ++p) {
        int rr = ty + p * 8;
        float val = T[tx][rr];                       // = W[k0+tx][n0+rr]
        unsigned h = f2b(val);
        size_t off = (size_t)(n0 + rr) * DM + k0 + tx;
        thi[off] = (u16)h;
        tlo[off] = (u16)f2b(val - b2f(h));
    }
}

// ---------------------------------------------------------------------------
// C[8192,512] = act((Ahi+Alo) @ (Bhi+Blo)^T + bias)*scale (+R)
// 128x128 tile, 4 waves x (4x4 of 16x16x32 MFMA), BK=32.
// OUTMODE: 0 = fp32 (+R), 1 = bf16 hi+lo planes, 2 = bf16 hi only.
// ---------------------------------------------------------------------------
template<int SPLIT, int RELU, int OUTMODE>
__global__ __launch_bounds__(256) void mm512(
    const u16* __restrict__ Ah_g, const u16* __restrict__ Al_g,
    const u16* __restrict__ Bh_g, const u16* __restrict__ Bl_g,
    const float* __restrict__ bias, const float* __restrict__ R,
    float scale, float* __restrict__ outF,
    u16* __restrict__ outHi, u16* __restrict__ outLo)
{
    __shared__ u16 Ah[128 * 40], Bh[128 * 40];
    __shared__ u16 Al[SPLIT ? 128 * 40 : 8], Bl[SPLIT ? 128 * 40 : 8];
    const int tid = threadIdx.x, lane = tid & 63, w = tid >> 6;
    const int wr = (w >> 1) * 64, wc = (w & 1) * 64;
    const int ml = lane & 15, q8 = (lane >> 4) * 8, q4 = (lane >> 4) * 4;
    const int row0 = blockIdx.x * 128, col0 = blockIdx.y * 128;
    const int sm = tid >> 2, sk = (tid & 3) * 8;

    f32x4 acc[4][4];
#pragma unroll
    for (int i = 0; i < 4; ++i)
#pragma unroll
        for (int j = 0; j < 4; ++j) acc[i][j] = {0.f, 0.f, 0.f, 0.f};

    for (int k0 = 0; k0 < DM; k0 += 32) {
#pragma unroll
        for (int p = 0; p < 2; ++p) {
            int m = sm + p * 64;
            *(uint4*)&Ah[m * 40 + sk] = *(const uint4*)&Ah_g[(size_t)(row0 + m) * DM + k0 + sk];
            *(uint4*)&Bh[m * 40 + sk] = *(const uint4*)&Bh_g[(size_t)(col0 + m) * DM + k0 + sk];
            if (SPLIT) {
                *(uint4*)&Al[m * 40 + sk] = *(const uint4*)&Al_g[(size_t)(row0 + m) * DM + k0 + sk];
                *(uint4*)&Bl[m * 40 + sk] = *(const uint4*)&Bl_g[(size_t)(col0 + m) * DM + k0 + sk];
            }
        }
        __syncthreads();
        bf16x8 a_h[4], b_h[4], a_l[4], b_l[4];
#pragma unroll
        for (int i = 0; i < 4; ++i) {
            a_h[i] = *(const bf16x8*)&Ah[(wr + i * 16 + ml) * 40 + q8];
            b_h[i] = *(const bf16x8*)&Bh[(wc + i * 16 + ml) * 40 + q8];
            if (SPLIT) {
                a_l[i] = *(const bf16x8*)&Al[(wr + i * 16 + ml) * 40 + q8];
                b_l[i] = *(const bf16x8*)&Bl[(wc + i * 16 + ml) * 40 + q8];
            }
        }
#pragma unroll
        for (int i = 0; i < 4; ++i)
#pragma unroll
            for (int j = 0; j < 4; ++j) {
                acc[i][j] = MFMA_B16(a_h[i], b_h[j], acc[i][j]);
                if (SPLIT) {
                    acc[i][j] = MFMA_B16(a_h[i], b_l[j], acc[i][j]);
                    acc[i][j] = MFMA_B16(a_l[i], b_h[j], acc[i][j]);
                    acc[i][j] = MFMA_B16(a_l[i], b_l[j], acc[i][j]);
                }
            }
        __syncthreads();
    }

    float bcol[4];
#pragma unroll
    for (int j = 0; j < 4; ++j) bcol[j] = bias[col0 + wc + j * 16 + ml];
#pragma unroll
    for (int i = 0; i < 4; ++i)
#pragma unroll
        for (int j = 0; j < 4; ++j)
#pragma unroll
            for (int r = 0; r < 4; ++r) {
                int gm = row0 + wr + i * 16 + q4 + r;
                int gn = col0 + wc + j * 16 + ml;
                float t = acc[i][j][r] + bcol[j];
                if (RELU) t = fmaxf(t, 0.f);
                t *= scale;
                size_t off = (size_t)gm * DM + gn;
                if (OUTMODE == 0) {
                    if (R) t += R[off];
                    outF[off] = t;
                } else if (OUTMODE == 1) {
                    unsigned hb = f2b(t);
                    outHi[off] = (u16)hb;
                    outLo[off] = (u16)f2b(t - b2f(hb));
                } else {
                    outHi[off] = (u16)f2b(t);
                }
            }
}

// ---------------------------------------------------------------------------
// Scores: S[128,128] tile of q_hb @ k_hb^T, split bf16 (4 MFMA combos), K=64.
// ---------------------------------------------------------------------------
__global__ __launch_bounds__(256) void score_mfma(
    const u16* __restrict__ qhi, const u16* __restrict__ qlo,
    const u16* __restrict__ khi, const u16* __restrict__ klo,
    float* __restrict__ scores, int hb0)
{
    __shared__ u16 Qh[128 * 40], Ql[128 * 40], Kh[128 * 40], Kl[128 * 40];
    const int tid = threadIdx.x, lane = tid & 63, w = tid >> 6;
    const int wr = (w >> 1) * 64, wc = (w & 1) * 64;
    const int ml = lane & 15, q8 = (lane >> 4) * 8, q4 = (lane >> 4) * 4;
    const int z = blockIdx.z, hb = hb0 + z, h = hb >> 3, b = hb & 7;
    const int r0 = blockIdx.x * 128, c0 = blockIdx.y * 128;
    const int sm = tid >> 2, sk = (tid & 3) * 8;
    const size_t base = (size_t)b * NSQ * DM + (size_t)h * HDIM;

    f32x4 acc[4][4];
#pragma unroll
    for (int i = 0; i < 4; ++i)
#pragma unroll
        for (int j = 0; j < 4; ++j) acc[i][j] = {0.f, 0.f, 0.f, 0.f};

    for (int k0 = 0; k0 < HDIM; k0 += 32) {
#pragma unroll
        for (int p = 0; p < 2; ++p) {
            int m = sm + p * 64;
            *(uint4*)&Qh[m * 40 + sk] = *(const uint4*)&qhi[base + (size_t)(r0 + m) * DM + k0 + sk];
            *(uint4*)&Ql[m * 40 + sk] = *(const uint4*)&qlo[base + (size_t)(r0 + m) * DM + k0 + sk];
            *(uint4*)&Kh[m * 40 + sk] = *(const uint4*)&khi[base + (size_t)(c0 + m) * DM + k0 + sk];
            *(uint4*)&Kl[m * 40 + sk] = *(const uint4*)&klo[base + (size_t)(c0 + m) * DM + k0 + sk];
        }
        __syncthreads();
        bf16x8 a_h[4], b_h[4], a_l[4], b_l[4];
#pragma unroll
        for (int i = 0; i < 4; ++i) {
            a_h[i] = *(const bf16x8*)&Qh[(wr + i * 16 + ml) * 40 + q8];
            b_h[i] = *(const bf16x8*)&Kh[(wc + i * 16 + ml) * 40 + q8];
            a_l[i] = *(const bf16x8*)&Ql[(wr + i * 16 + ml) * 40 + q8];
            b_l[i] = *(const bf16x8*)&Kl[(wc + i * 16 + ml) * 40 + q8];
        }
#pragma unroll
        for (int i = 0; i < 4; ++i)
#pragma unroll
            for (int j = 0; j < 4; ++j) {
                acc[i][j] = MFMA_B16(a_h[i], b_h[j], acc[i][j]);
                acc[i][j] = MFMA_B16(a_h[i], b_l[j], acc[i][j]);
                acc[i][j] = MFMA_B16(a_l[i], b_h[j], acc[i][j]);
                acc[i][j] = MFMA_B16(a_l[i], b_l[j], acc[i][j]);
            }
        __syncthreads();
    }
#pragma unroll
    for (int i = 0; i < 4; ++i)
#pragma unroll
        for (int j = 0; j < 4; ++j)
#pragma unroll
            for (int r = 0; r < 4; ++r)
                scores[((size_t)z * NSQ + r0 + wr + i * 16 + q4 + r) * NSQ + c0 + wc + j * 16 + ml]
                    = acc[i][j][r];
}

// ---------------------------------------------------------------------------
// Exact top-32 + softmax + PV. One wave per query row.
// v2: mu/sigma initial bounds, ballot-per-candidate counting, ballot-prefix
// compaction, bf16 V gather, bf16 output.
// ---------------------------------------------------------------------------
__global__ __launch_bounds__(256) void select_pv(
    const float* __restrict__ scores, const u16* __restrict__ vhi,
    u16* __restrict__ ao, int hb0)
{
    __shared__ float pv_[4][TOPK];
    __shared__ int   pi_[4][TOPK];
    const int tid = threadIdx.x, w = tid >> 6, lane = tid & 63;
    const int z = blockIdx.y, hb = hb0 + z, h = hb >> 3, b = hb & 7;
    const int row = blockIdx.x * 4 + w;
    const float* srow = scores + ((size_t)z * NSQ + row) * NSQ;

    float f[16]; unsigned u[16];
    float s1 = 0.f, s2 = 0.f;
#pragma unroll
    for (int i = 0; i < 16; ++i) {
        f[i] = srow[i * 64 + lane];
        s1 += f[i];
        s2 = fmaf(f[i], f[i], s2);
    }
#pragma unroll
    for (int o = 32; o; o >>= 1) { s1 += __shfl_xor(s1, o); s2 += __shfl_xor(s2, o); }
    float mu = s1 * (1.f / 1024.f);
    float sg = sqrtf(fmaxf(s2 * (1.f / 1024.f) - mu * mu, 0.f)) + 1e-20f;
#pragma unroll
    for (int i = 0; i < 16; ++i) u[i] = ordu(f[i]);

    auto cnt = [&](unsigned t) -> int {
        int tot = 0;
#pragma unroll
        for (int i = 0; i < 16; ++i) tot += __popcll(__ballot(u[i] > t));
        return tot;
    };

    float tl = mu + 1.2f * sg, dstep = 0.7f * sg;
    unsigned lo = ordu(tl);
    int clo = cnt(lo);
    while (clo < TOPK) { tl -= dstep; dstep *= 2.f; lo = ordu(tl); clo = cnt(lo); }
    float th = mu + 4.0f * sg, ustep = 2.0f * sg;
    unsigned hi = ordu(th);
    int chi = cnt(hi);
    while (chi >= TOPK) { lo = hi; clo = chi; th += ustep; ustep *= 2.f; hi = ordu(th); chi = cnt(hi); }
    if (clo > TOPK) {
        while (hi - lo > 1u) {
            unsigned mid = lo + ((hi - lo) >> 1);
            int c = cnt(mid);
            if (c >= TOPK) { lo = mid; clo = c; if (c == TOPK) break; }
            else hi = mid;
        }
    }

    unsigned selm = 0;
#pragma unroll
    for (int i = 0; i < 16; ++i) if (u[i] > lo) selm |= (1u << i);

    // tie-prune at the boundary value (drop largest indices first, matching lax.top_k)
    int nsel = clo;
    unsigned bhi = lo + 1u;
    while (nsel > TOPK) {
        int myidx = -1, myslot = 0;
#pragma unroll
        for (int i = 0; i < 16; ++i)
            if (((selm >> i) & 1u) && u[i] == bhi) { myidx = i * 64 + lane; myslot = i; }
        int mx = myidx;
#pragma unroll
        for (int o = 32; o; o >>= 1) mx = max(mx, __shfl_xor(mx, o));
        if (myidx == mx && myidx >= 0) selm &= ~(1u << myslot);
        nsel--;
    }

    float lm = -INFINITY;
#pragma unroll
    for (int i = 0; i < 16; ++i) if ((selm >> i) & 1u) lm = fmaxf(lm, f[i]);
#pragma unroll
    for (int o = 32; o; o >>= 1) lm = fmaxf(lm, __shfl_xor(lm, o));
    float e[16], es = 0.f;
#pragma unroll
    for (int i = 0; i < 16; ++i) {
        e[i] = ((selm >> i) & 1u) ? __expf(f[i] - lm) : 0.f;
        es += e[i];
    }
#pragma unroll
    for (int o = 32; o; o >>= 1) es += __shfl_xor(es, o);
    float inv = 1.f / es;

    unsigned long long ltm = (1ull << lane) - 1ull;
    int basec = 0;
#pragma unroll
    for (int i = 0; i < 16; ++i) {
        unsigned long long m = __ballot((selm >> i) & 1u);
        if ((selm >> i) & 1u) {
            int slot = basec + __popcll(m & ltm);
            pv_[w][slot] = e[i] * inv;
            pi_[w][slot] = i * 64 + lane;
        }
        basec += __popcll(m);
    }
    __syncthreads();

    float acc = 0.f;
    const u16* vb = vhi + (size_t)b * NSQ * DM + (size_t)h * HDIM + lane;
    const float* pvr = pv_[w];
    const int*   pir = pi_[w];
#pragma unroll 8
    for (int t = 0; t < TOPK; ++t)
        acc = fmaf(pvr[t], b2f(vb[(size_t)pir[t] * DM]), acc);
    ao[((size_t)b * NSQ + row) * DM + (size_t)h * HDIM + lane] = (u16)f2b(acc);
}

// ---------------------------------------------------------------------------
// LayerNorm: out = LN(a [+ bf16 addb]) * g + be; optional fp32 + bf16-hi outs
// ---------------------------------------------------------------------------
__global__ __launch_bounds__(256) void ln_fused(
    const float* __restrict__ a, const u16* __restrict__ addb,
    const float* __restrict__ g, const float* __restrict__ be,
    float* __restrict__ outF, u16* __restrict__ outHi)
{
    __shared__ float red[4][2];
    const int row = blockIdx.x, tid = threadIdx.x, w = tid >> 6;
    float2 v = ((const float2*)(a + (size_t)row * DM))[tid];
    if (addb) {
        ushort2 ab = ((const ushort2*)(addb + (size_t)row * DM))[tid];
        v.x += b2f(ab.x); v.y += b2f(ab.y);
    }
    float s = v.x + v.y, q = v.x * v.x + v.y * v.y;
#pragma unroll
    for (int o = 32; o; o >>= 1) { s += __shfl_xor(s, o); q += __shfl_xor(q, o); }
    if ((tid & 63) == 0) { red[w][0] = s; red[w][1] = q; }
    __syncthreads();
    float S = red[0][0] + red[1][0] + red[2][0] + red[3][0];
    float Q = red[0][1] + red[1][1] + red[2][1] + red[3][1];
    float mu = S * (1.f / DM);
    float var = Q * (1.f / DM) - mu * mu;
    float rs = rsqrtf(var + 1e-5f);
    float2 gv = ((const float2*)g)[tid];
    float2 bv = ((const float2*)be)[tid];
    float2 o;
    o.x = (v.x - mu) * rs * gv.x + bv.x;
    o.y = (v.y - mu) * rs * gv.y + bv.y;
    if (outF) ((float2*)(outF + (size_t)row * DM))[tid] = o;
    if (outHi) {
        ushort2 hv; hv.x = (u16)f2b(o.x); hv.y = (u16)f2b(o.y);
        ((ushort2*)(outHi + (size_t)row * DM))[tid] = hv;
    }
}

// ---------------------------------------------------------------------------
extern "C" void kernel_launch(void* const* d_in, const int* in_sizes, int n_in,
                              void* d_out, int out_size, void* d_ws, size_t ws_size,
                              hipStream_t stream) {
    const float* src = (const float*)d_in[0];
    const float* tgt = (const float*)d_in[1];
    const float* Wq  = (const float*)d_in[2];
    const float* bq  = (const float*)d_in[3];
    const float* Wk  = (const float*)d_in[4];
    const float* bk  = (const float*)d_in[5];
    const float* Wv  = (const float*)d_in[6];
    const float* bv  = (const float*)d_in[7];
    const float* W1  = (const float*)d_in[8];
    const float* b1  = (const float*)d_in[9];
    const float* W2  = (const float*)d_in[10];
    const float* b2  = (const float*)d_in[11];
    const float* g1  = (const float*)d_in[12];
    const float* be1 = (const float*)d_in[13];
    const float* g2  = (const float*)d_in[14];
    const float* be2 = (const float*)d_in[15];

    // workspace map (bytes, MB offsets). Minimum required: 85 MB.
    const size_t WPLANE = (size_t)DM * DM;
    u16* wt  = (u16*)d_ws;
    u16* wqh = wt;              u16* wql = wt + WPLANE;
    u16* wkh = wt + 2 * WPLANE; u16* wkl = wt + 3 * WPLANE;
    u16* wvh = wt + 4 * WPLANE; u16* wvl = wt + 5 * WPLANE;
    u16* w1h = wt + 6 * WPLANE; u16* w1l = wt + 7 * WPLANE;
    u16* w2h = wt + 8 * WPLANE; u16* w2l = wt + 9 * WPLANE;
    auto at = [&](size_t mb) { return (char*)d_ws + (mb << 20); };
    u16* Phi = (u16*)at(5);    // input split planes (tgt, then src)
    u16* Plo = (u16*)at(13);
    u16* qhi = (u16*)at(21);   // later reused as x_hi
    u16* khi = (u16*)at(29);   // later reused as h_hi
    u16* qlo = (u16*)at(37);   // later (with klo) reused as fp32 ff2 out
    u16* klo = (u16*)at(45);
    u16* vhi = (u16*)at(53);
    u16* aob = (u16*)at(61);
    float* xb = (float*)at(69);           // 16 MB fp32
    float* f2 = (float*)at(37);           // aliases qlo+klo (post-attention)
    float* sc; int slab;
    if (ws_size >= ((size_t)149 << 20)) { sc = (float*)at(85); slab = 16; }
    else                                { sc = xb;             slab = 4;  }

    dim3 blk(256);
    const float qscale = 0.04419417382415922f;  // 1/sqrt(512)

    wconv<<<dim3(16, 16), blk, 0, stream>>>(Wq, wqh, wql);
    wconv<<<dim3(16, 16), blk, 0, stream>>>(Wk, wkh, wkl);
    wconv<<<dim3(16, 16), blk, 0, stream>>>(Wv, wvh, wvl);
    wconv<<<dim3(16, 16), blk, 0, stream>>>(W1, w1h, w1l);
    wconv<<<dim3(16, 16), blk, 0, stream>>>(W2, w2h, w2l);

    conv_split<<<4096, blk, 0, stream>>>(tgt, Phi, Plo);
    mm512<1, 0, 1><<<dim3(64, 4), blk, 0, stream>>>(Phi, Plo, wqh, wql, bq, nullptr, qscale,
                                                    nullptr, qhi, qlo);
    conv_split<<<4096, blk, 0, stream>>>(src, Phi, Plo);
    mm512<1, 0, 1><<<dim3(64, 4), blk, 0, stream>>>(Phi, Plo, wkh, wkl, bk, nullptr, 1.f,
                                                    nullptr, khi, klo);
    mm512<0, 0, 2><<<dim3(64, 4), blk, 0, stream>>>(Phi, nullptr, wvh, nullptr, bv, nullptr, 1.f,
                                                    nullptr, vhi, nullptr);

    for (int hb0 = 0; hb0 < 64; hb0 += slab) {
        score_mfma<<<dim3(8, 8, slab), blk, 0, stream>>>(qhi, qlo, khi, klo, sc, hb0);
        select_pv<<<dim3(256, slab), blk, 0, stream>>>(sc, vhi, aob, hb0);
    }

    ln_fused<<<8192, blk, 0, stream>>>(tgt, aob, g1, be1, xb, qhi);           // x (fp32 + bf16)
    mm512<0, 1, 2><<<dim3(64, 4), blk, 0, stream>>>(qhi, nullptr, w1h, nullptr, b1, nullptr, 1.f,
                                                    nullptr, khi, nullptr);   // h = relu(x@W1+b1)
    mm512<0, 0, 0><<<dim3(64, 4), blk, 0, stream>>>(khi, nullptr, w2h, nullptr, b2, xb, 1.f,
                                                    f2, nullptr, nullptr);    // x + h@W2+b2
    ln_fused<<<8192, blk, 0, stream>>>(f2, nullptr, g2, be2, (float*)d_out, nullptr);
}